// Round 4
// baseline (109.122 us; speedup 1.0000x reference)
//
#include <hip/hip_runtime.h>

#define NB 128
#define NTOK 201

// Grid = 512 blocks x 1024 threads, exactly 2 blocks/CU.
//  - "heavy" blocks (even bid < 256): merged e0+e1 chains for batch b=bid>>1.
//    Shared 198-wide state (x rows/cols {0,1} U [5,201)); u0 has a hard 0 at
//    slot 1, u1 at slot 0, so one load of A feeds both chains' FMAs exactly.
//  - "light" blocks: e=3 (odd bid<256), e=2 (bid 256..383), e=4 (bid 384..511).
__global__ __launch_bounds__(1024) void part_att_kernel(
    const float* __restrict__ x, float* __restrict__ out)
{
    const int bid = blockIdx.x;
    const int tid = threadIdx.x;
    const size_t plane = (size_t)NTOK * NTOK;

    __shared__ float rv[256];
    __shared__ int   rix[256];

    if (bid < 256 && (bid & 1) == 0) {
        // ---------------- heavy: merged e0 + e1 ----------------
        const int b = bid >> 1;
        const float* xb = x + (size_t)b * plane;
        const int lo = 5;                       // window [5,201)
        __shared__ float u0[2][200], u1[2][200];
        __shared__ float p0[1024], p1[1024];

        const int j  = tid & 255;               // shared col index 0..197 valid
        const int rg = tid >> 8;                // 0..3 row groups
        const bool act = j < 198;
        const int c = (j < 2) ? j : 3 + j;      // x col: 0,1, then 5..200

        if (tid < 198) {
            const int cc = (tid < 2) ? tid : 3 + tid;
            const float* L11 = xb + (size_t)(11 * NB) * plane;
            u0[0][tid] = (tid == 1) ? 0.f : L11[cc];           // row 0 of layer 11
            u1[0][tid] = (tid == 0) ? 0.f : L11[NTOK + cc];    // row 1 of layer 11
        }
        __syncthreads();

        int cur = 0;
        for (int l = 10; l >= 0; --l) {
            const float* A = xb + (size_t)(l * NB) * plane;
            float s0 = 0.f, s1 = 0.f, t0 = 0.f, t1 = 0.f;
            if (act) {
                const float* U0 = u0[cur];
                const float* U1 = u1[cur];
                int ri = rg;
                if (ri < 2) {                   // shared rows 0,1 -> x rows 0,1
                    const float a = A[(size_t)ri * NTOK + c];
                    s0 += U0[ri] * a; s1 += U1[ri] * a;
                    ri += 4;
                }
                const float* rp = A + (size_t)(3 + ri) * NTOK + c;  // x row 3+ri
                const int step = 4 * NTOK;
                for (; ri + 4 < 198; ri += 8) {
                    const float a  = rp[0];
                    const float bv = rp[step];
                    s0 += U0[ri]     * a;  s1 += U1[ri]     * a;
                    t0 += U0[ri + 4] * bv; t1 += U1[ri + 4] * bv;
                    rp += 2 * step;
                }
                for (; ri < 198; ri += 4) {
                    const float a = rp[0];
                    s0 += U0[ri] * a; s1 += U1[ri] * a;
                    rp += step;
                }
            }
            p0[tid] = s0 + t0;
            p1[tid] = s1 + t1;
            __syncthreads();
            if (tid < 198) {
                const float v0 = p0[tid] + p0[tid+256] + p0[tid+512] + p0[tid+768];
                const float v1 = p1[tid] + p1[tid+256] + p1[tid+512] + p1[tid+768];
                u0[1 - cur][tid] = (tid == 1) ? 0.f : v0;
                u1[1 - cur][tid] = (tid == 0) ? 0.f : v1;
            }
            __syncthreads();
            cur ^= 1;
        }

        // argmax per chain over shared cols [2,198); sliced row = idx-2, +lo.
        for (int chain = 0; chain < 2; ++chain) {
            const float* U = chain ? u1[cur] : u0[cur];
            if (tid < 256) {
                float v = -INFINITY; int idx = 0x7fffffff;
                if (tid >= 2 && tid < 198) { v = U[tid]; idx = tid; }
                rv[tid] = v; rix[tid] = idx;
            }
            __syncthreads();
            for (int s = 128; s > 0; s >>= 1) {
                if (tid < s) {
                    const float v2 = rv[tid + s]; const int i2 = rix[tid + s];
                    if (v2 > rv[tid] || (v2 == rv[tid] && i2 < rix[tid])) {
                        rv[tid] = v2; rix[tid] = i2;
                    }
                }
                __syncthreads();
            }
            if (tid == 0) {
                out[chain * NB + b]       = rv[0];
                out[640 + chain * NB + b] = (float)((rix[0] - 2) + lo);
            }
            __syncthreads();
        }
    } else {
        // ---------------- light: e in {2,3,4}, M = 99 ----------------
        int e, lo, b;
        if (bid < 256)      { e = 3; lo = 54;  b = bid >> 1; }
        else if (bid < 384) { e = 2; lo = 5;   b = bid - 256; }
        else                { e = 4; lo = 103; b = bid - 384; }
        const int M = 99;
        const float* xb = x + (size_t)b * plane;
        __shared__ float ub[2][104];
        __shared__ float part[1024];

        const int j  = tid & 127;
        const int rg = tid >> 7;                // 0..7
        const bool act = j < M;
        const int c = (j == 0) ? e : (lo + j - 1);

        if (tid < M) {
            const int c0 = (tid == 0) ? e : (lo + tid - 1);
            ub[0][tid] = xb[(size_t)(11 * NB) * plane + (size_t)e * NTOK + c0];
        }
        __syncthreads();

        int cur = 0;
        for (int l = 10; l >= 0; --l) {
            const float* A = xb + (size_t)(l * NB) * plane;
            float a0 = 0.f, a1 = 0.f;
            if (act) {
                const float* U = ub[cur];
                int i = rg;
                if (rg == 0) { a0 = U[0] * A[(size_t)e * NTOK + c]; i = 8; }
                const float* rp = A + (size_t)(lo + i - 1) * NTOK + c;
                const int step = 8 * NTOK;
                for (; i + 8 < M; i += 16) {
                    a0 += U[i]     * rp[0];
                    a1 += U[i + 8] * rp[step];
                    rp += 2 * step;
                }
                for (; i < M; i += 8) { a0 += U[i] * rp[0]; rp += step; }
            }
            part[tid] = a0 + a1;
            __syncthreads();
            if (tid < M) {
                float s = 0.f;
                #pragma unroll
                for (int g = 0; g < 8; ++g) s += part[g * 128 + tid];
                ub[1 - cur][tid] = s;
            }
            __syncthreads();
            cur ^= 1;
        }

        if (tid < 256) {
            float v = -INFINITY; int idx = 0x7fffffff;
            if (tid >= 1 && tid < M) { v = ub[cur][tid]; idx = tid; }
            rv[tid] = v; rix[tid] = idx;
        }
        __syncthreads();
        for (int s = 128; s > 0; s >>= 1) {
            if (tid < s) {
                const float v2 = rv[tid + s]; const int i2 = rix[tid + s];
                if (v2 > rv[tid] || (v2 == rv[tid] && i2 < rix[tid])) {
                    rv[tid] = v2; rix[tid] = i2;
                }
            }
            __syncthreads();
        }
        if (tid == 0) {
            out[e * NB + b]       = rv[0];
            out[640 + e * NB + b] = (float)((rix[0] - 1) + lo);
        }
    }
}

extern "C" void kernel_launch(void* const* d_in, const int* in_sizes, int n_in,
                              void* d_out, int out_size, void* d_ws, size_t ws_size,
                              hipStream_t stream) {
    (void)in_sizes; (void)n_in; (void)d_ws; (void)ws_size; (void)out_size;
    const float* x = (const float*)d_in[0];
    float* out = (float*)d_out;
    part_att_kernel<<<dim3(512), dim3(1024), 0, stream>>>(x, out);
}